// Round 1
// baseline (674.310 us; speedup 1.0000x reference)
//
#include <hip/hip_runtime.h>
#include <hip/hip_bf16.h>
#include <math.h>

#define D 64
#define K 1024
#define N_VEC 262144  // 64*64*64

// ---------------------------------------------------------------------------
// ws layout (floats/uints):
//   [0 .. K)      : unsigned int counts
//   [K .. 2K)     : float cnorm (|c|^2 per code)
//   [2K]          : float sum of squared error
// ---------------------------------------------------------------------------

__global__ __launch_bounds__(256) void vq_cnorm_kernel(
    const float* __restrict__ cb, float* __restrict__ cnorm) {
  int k = blockIdx.x * blockDim.x + threadIdx.x;
  if (k < K) {
    const float* c = cb + (size_t)k * D;
    float s = 0.f;
#pragma unroll
    for (int j = 0; j < D; ++j) s = fmaf(c[j], c[j], s);
    cnorm[k] = s;
  }
}

__global__ __launch_bounds__(256) void vq_argmin_kernel(
    const float* __restrict__ x, const float* __restrict__ cb,
    const float* __restrict__ cnorm, float* __restrict__ tok_out,
    unsigned int* __restrict__ counts) {
  __shared__ unsigned int hist[K];
  for (int i = threadIdx.x; i < K; i += 256) hist[i] = 0u;
  __syncthreads();

  int vid = blockIdx.x * 256 + threadIdx.x;

  // load this thread's vector into registers (16 x float4)
  float xr[D];
  const float4* xp = reinterpret_cast<const float4*>(x + (size_t)vid * D);
#pragma unroll
  for (int j = 0; j < 16; ++j) {
    float4 v = xp[j];
    xr[4 * j + 0] = v.x;
    xr[4 * j + 1] = v.y;
    xr[4 * j + 2] = v.z;
    xr[4 * j + 3] = v.w;
  }
  float xx = 0.f;
#pragma unroll
  for (int j = 0; j < D; ++j) xx = fmaf(xr[j], xr[j], xx);

  float best = 3.4e38f;
  int bidx = 0;
  for (int k = 0; k < K; ++k) {
    const float* c = cb + (size_t)k * D;  // wave-uniform -> scalar loads
    float acc = 0.f;
#pragma unroll
    for (int j = 0; j < D; ++j) acc = fmaf(xr[j], c[j], acc);
    float dist = (xx + cnorm[k]) - 2.0f * acc;
    bool lt = dist < best;           // strict <  => first-min tie-break (argmin)
    best = lt ? dist : best;
    bidx = lt ? k : bidx;
  }

  tok_out[vid] = (float)bidx;
  atomicAdd(&hist[bidx], 1u);
  __syncthreads();
  for (int i = threadIdx.x; i < K; i += 256) {
    unsigned int h = hist[i];
    if (h) atomicAdd(&counts[i], h);
  }
}

__device__ __forceinline__ float block_reduce_sum_256(float v) {
#pragma unroll
  for (int o = 32; o > 0; o >>= 1) v += __shfl_down(v, o, 64);
  __shared__ float s[4];
  int lane = threadIdx.x & 63;
  int w = threadIdx.x >> 6;
  if (lane == 0) s[w] = v;
  __syncthreads();
  float r = 0.f;
  if (threadIdx.x == 0) r = s[0] + s[1] + s[2] + s[3];
  return r;  // valid on thread 0 only
}

__global__ __launch_bounds__(256) void vq_gather_kernel(
    const float* __restrict__ x, const float* __restrict__ cb,
    const float* __restrict__ tok, float* __restrict__ outq,
    float* __restrict__ sq_accum) {
  const int total4 = N_VEC * (D / 4);  // number of float4 elements
  float sq = 0.f;
  for (int idx4 = blockIdx.x * 256 + threadIdx.x; idx4 < total4;
       idx4 += gridDim.x * 256) {
    int vid = idx4 >> 4;      // D/4 == 16 float4 per vector
    int j4 = idx4 & 15;
    int t = (int)tok[vid];
    float4 xv = reinterpret_cast<const float4*>(x)[idx4];
    float4 cv = reinterpret_cast<const float4*>(cb + (size_t)t * D)[j4];
    float dx0 = cv.x - xv.x;
    float dx1 = cv.y - xv.y;
    float dx2 = cv.z - xv.z;
    float dx3 = cv.w - xv.w;
    float4 q;
    q.x = xv.x + dx0;  // quantized_st = x + (q - x), matches reference arithmetic
    q.y = xv.y + dx1;
    q.z = xv.z + dx2;
    q.w = xv.w + dx3;
    reinterpret_cast<float4*>(outq)[idx4] = q;
    sq = fmaf(dx0, dx0, sq);
    sq = fmaf(dx1, dx1, sq);
    sq = fmaf(dx2, dx2, sq);
    sq = fmaf(dx3, dx3, sq);
  }
  float bs = block_reduce_sum_256(sq);
  if (threadIdx.x == 0) atomicAdd(sq_accum, bs);
}

__global__ __launch_bounds__(256) void vq_finalize_kernel(
    const unsigned int* __restrict__ counts, const float* __restrict__ sq_accum,
    float* __restrict__ out_scalars) {
  float h = 0.f;
  for (int i = threadIdx.x; i < K; i += 256) {
    float p = (float)counts[i] / (float)N_VEC;
    h -= p * logf(p + 1e-10f);
  }
  float hs = block_reduce_sum_256(h);
  if (threadIdx.x == 0) {
    float m = sq_accum[0] / (float)((size_t)N_VEC * D);
    out_scalars[0] = 1.25f * m;  // vq_loss = commitment + codebook
    out_scalars[1] = 0.25f * m;  // commitment_loss
    out_scalars[2] = m;          // codebook_loss
    out_scalars[3] = expf(hs);   // perplexity
  }
}

extern "C" void kernel_launch(void* const* d_in, const int* in_sizes, int n_in,
                              void* d_out, int out_size, void* d_ws,
                              size_t ws_size, hipStream_t stream) {
  const float* x = (const float*)d_in[0];
  const float* cb = (const float*)d_in[1];

  float* outq = (float*)d_out;                    // N_VEC * D
  float* tok = outq + (size_t)N_VEC * D;          // N_VEC (as float)
  float* scal = tok + N_VEC;                      // 4 scalars

  unsigned int* counts = (unsigned int*)d_ws;     // K
  float* cnorm = (float*)d_ws + K;                // K
  float* sq = (float*)d_ws + 2 * K;               // 1

  // zero counts + sq every call (graph replays don't re-poison)
  hipMemsetAsync(d_ws, 0, (size_t)(2 * K + 1) * sizeof(float), stream);

  vq_cnorm_kernel<<<(K + 255) / 256, 256, 0, stream>>>(cb, cnorm);
  vq_argmin_kernel<<<N_VEC / 256, 256, 0, stream>>>(x, cb, cnorm, tok, counts);
  vq_gather_kernel<<<4096, 256, 0, stream>>>(x, cb, tok, outq, sq);
  vq_finalize_kernel<<<1, 256, 0, stream>>>(counts, sq, scal);
}